// Round 6
// baseline (1270.285 us; speedup 1.0000x reference)
//
#include <hip/hip_runtime.h>
#include <hip/hip_bf16.h>

#define DIM   384
#define NWIN  49
#define HEADS 12
#define SCALE 0.17677669529663687f

typedef unsigned short ushort;
using bf16x8 = __attribute__((ext_vector_type(8))) short;
using u16x4  = __attribute__((ext_vector_type(4))) ushort;
using f32x4  = __attribute__((ext_vector_type(4))) float;

__device__ __forceinline__ ushort f2bf(float f) {
  unsigned u = __float_as_uint(f);
  u += 0x7fff + ((u >> 16) & 1);          // RNE
  return (ushort)(u >> 16);
}

// prep: bf16 weights (Wq prescaled), scaled qkv bias,
// bias+mask in MFMA-fragment float4 layout bmF[wdx][h][wq][kt][lane][r]
__global__ void prep_kernel(const float* __restrict__ qkv_w, const float* __restrict__ proj_w,
                            const float* __restrict__ bias_table, const int* __restrict__ rel_index,
                            const float* __restrict__ mask, const float* __restrict__ qkv_b,
                            ushort* __restrict__ wqb, ushort* __restrict__ wpb,
                            float* __restrict__ qbF, float* __restrict__ bmF) {
  int i0 = blockIdx.x * 256 + threadIdx.x;
  int stride = gridDim.x * 256;
  for (int i = i0; i < 1152 * 384; i += stride) {
    float v = qkv_w[i];
    if (i < 384 * 384) v *= SCALE;                 // fold softmax scale into Wq
    wqb[i] = f2bf(v);
  }
  for (int i = i0; i < 384 * 384; i += stride) wpb[i] = f2bf(proj_w[i]);
  for (int i = i0; i < 1152; i += stride) qbF[i] = qkv_b[i] * (i < 384 ? SCALE : 1.f);
  // bmF: [wdx][h][wq][kt][lane][r], masking baked in
  for (int i = i0; i < 64 * HEADS * 4 * 4 * 64 * 4; i += stride) {
    int r = i & 3, lane = (i >> 2) & 63, kt = (i >> 8) & 3, wq = (i >> 10) & 3;
    int hw = i >> 12;
    int h = hw % HEADS, wdx = hw / HEADS;
    int q = wq * 16 + (lane >> 4) * 4 + r;
    int key = kt * 16 + (lane & 15);
    float v;
    if (q < NWIN)
      v = (key < NWIN) ? bias_table[rel_index[q * NWIN + key] * HEADS + h]
                         + mask[wdx * (NWIN * NWIN) + q * NWIN + key]
                       : -3.0e38f;
    else
      v = 0.f;
    bmF[i] = v;
  }
}

// One window per block, 256 threads (4 waves). LDS 52.5 KB -> 2+ blocks/CU.
// Weights stream global->VGPR (L1/L2-hot), NO LDS staging, NO staging barriers.
__global__ __launch_bounds__(256, 2) void winattn_kernel(
    const float* __restrict__ x, const float* __restrict__ qbF,
    const float* __restrict__ proj_b, const ushort* __restrict__ wqb,
    const ushort* __restrict__ wpb, const float* __restrict__ bmF,
    float* __restrict__ out)
{
  __shared__ ushort qs[64 * 40];        // q rows (later aliased by P)
  __shared__ ushort ks[64 * 40];        // k rows
  __shared__ ushort vt[32 * 72];        // v^T [d][tok]
  __shared__ ushort ao[NWIN * 384];     // x (swizzled), overwritten by attn-out

  const int blk = blockIdx.x;
  const int tid = threadIdx.x;
  const int w = tid >> 6, l = tid & 63;
  const int c = l & 15, g = l >> 4;
  const int wm = w >> 1, wn = w & 1;    // GEMM wave grid: 2M x 2N (tile 32x16)
  const int wq = w;                     // attention: wave = q-tile
  const int wdx = blk & 63;
  const float LOG2E = 1.4426950408889634f;

  // ---- stage x -> swizzled bf16 ao[49][384]; granule ^= (row&15)
  {
    const float* xb = x + (size_t)blk * (NWIN * DIM);
    for (int i = tid; i < 4704; i += 256) {        // 4704 float4 = 49*384 floats
      float4 f = ((const float4*)xb)[i];
      int row = i / 96, c4 = i - row * 96;
      int gr = (c4 >> 1) ^ (row & 15);
      u16x4 v4 = { f2bf(f.x), f2bf(f.y), f2bf(f.z), f2bf(f.w) };
      *(u16x4*)&ao[row * 384 + (gr << 3) + (c4 & 1) * 4] = v4;
    }
  }
  __syncthreads();

  // ---- A fragments in registers (rows >= 49 zero)
  bf16x8 areg[2][12] = {};
  #pragma unroll
  for (int mt = 0; mt < 2; ++mt) {
    int row = wm * 32 + mt * 16 + c;
    if (row < NWIN) {
      #pragma unroll
      for (int kg = 0; kg < 12; ++kg)
        areg[mt][kg] = *(const bf16x8*)&ao[row * 384 + (((kg * 4 + g) ^ (row & 15)) << 3)];
    }
  }

  // ================= per-head: QKV (B from global) + attention =================
  for (int h = 0; h < HEADS; ++h) {
    // --- q, k, v GEMMs: wave computes rows wm*32..+31, cols wn*16..+15 of each
    #pragma unroll
    for (int m = 0; m < 3; ++m) {
      const int d = wn * 16 + c;
      const ushort* bsrc = wqb + ((size_t)(m * 384 + h * 32 + d)) * DIM + g * 8;
      bf16x8 breg[12];
      #pragma unroll
      for (int kg = 0; kg < 12; ++kg)
        breg[kg] = *(const bf16x8*)(bsrc + kg * 32);
      f32x4 acc[2] = {};
      #pragma unroll
      for (int kg = 0; kg < 12; ++kg) {
        acc[0] = __builtin_amdgcn_mfma_f32_16x16x32_bf16(areg[0][kg], breg[kg], acc[0], 0, 0, 0);
        acc[1] = __builtin_amdgcn_mfma_f32_16x16x32_bf16(areg[1][kg], breg[kg], acc[1], 0, 0, 0);
      }
      float qb_ = qbF[m * 384 + h * 32 + d];
      #pragma unroll
      for (int mt = 0; mt < 2; ++mt) {
        #pragma unroll
        for (int r = 0; r < 4; ++r) {
          int tok = wm * 32 + mt * 16 + g * 4 + r;
          float v = acc[mt][r] + qb_;
          if (m == 0)      qs[tok * 40 + d] = f2bf(v);
          else if (m == 1) ks[tok * 40 + d] = f2bf(v);
          else             vt[d * 72 + tok] = f2bf(v);
        }
      }
    }
    __syncthreads();                   // q/k/v visible to all waves

    // --- attention: wave wq owns q rows wq*16..+15
    const f32x4* bw4 = (const f32x4*)(bmF + ((((size_t)(wdx * HEADS + h)) * 4 + wq) * 4 * 64 + l) * 4);
    f32x4 bmv[4];
    #pragma unroll
    for (int kt = 0; kt < 4; ++kt) bmv[kt] = bw4[kt * 64];

    f32x4 sacc[4] = {};
    {
      bf16x8 aq = *(const bf16x8*)&qs[(wq * 16 + c) * 40 + g * 8];
      #pragma unroll
      for (int kt = 0; kt < 4; ++kt) {
        bf16x8 bk = *(const bf16x8*)&ks[(kt * 16 + c) * 40 + g * 8];
        sacc[kt] = __builtin_amdgcn_mfma_f32_16x16x32_bf16(aq, bk, sacc[kt], 0, 0, 0);
      }
    }
    float p[4][4];
    #pragma unroll
    for (int r = 0; r < 4; ++r) {
      float s0 = sacc[0][r] + bmv[0][r], s1 = sacc[1][r] + bmv[1][r];
      float s2 = sacc[2][r] + bmv[2][r], s3 = sacc[3][r] + bmv[3][r];
      float mx = fmaxf(fmaxf(s0, s1), fmaxf(s2, s3));
      mx = fmaxf(mx, __shfl_xor(mx, 1, 64));
      mx = fmaxf(mx, __shfl_xor(mx, 2, 64));
      mx = fmaxf(mx, __shfl_xor(mx, 4, 64));
      mx = fmaxf(mx, __shfl_xor(mx, 8, 64));
      float p0 = __builtin_exp2f((s0 - mx) * LOG2E);
      float p1 = __builtin_exp2f((s1 - mx) * LOG2E);
      float p2 = __builtin_exp2f((s2 - mx) * LOG2E);
      float p3 = __builtin_exp2f((s3 - mx) * LOG2E);
      float sum = p0 + p1 + p2 + p3;
      sum += __shfl_xor(sum, 1, 64);
      sum += __shfl_xor(sum, 2, 64);
      sum += __shfl_xor(sum, 4, 64);
      sum += __shfl_xor(sum, 8, 64);
      float inv = 1.0f / sum;
      p[0][r] = p0 * inv; p[1][r] = p1 * inv; p[2][r] = p2 * inv; p[3][r] = p3 * inv;
    }
    // PV via P staged in own qs rows (wave-private, within-wave ordered)
    f32x4 pacc[2] = {};
    #pragma unroll
    for (int kkh = 0; kkh < 2; ++kkh) {
      #pragma unroll
      for (int t = 0; t < 2; ++t) {
        int kt = kkh * 2 + t;
        #pragma unroll
        for (int r = 0; r < 4; ++r)
          qs[(wq * 16 + g * 4 + r) * 40 + t * 16 + c] = f2bf(p[kt][r]);
      }
      bf16x8 ap = *(const bf16x8*)&qs[(wq * 16 + c) * 40 + g * 8];
      #pragma unroll
      for (int dt = 0; dt < 2; ++dt) {
        bf16x8 bv = *(const bf16x8*)&vt[(dt * 16 + c) * 72 + kkh * 32 + g * 8];
        pacc[dt] = __builtin_amdgcn_mfma_f32_16x16x32_bf16(ap, bv, pacc[dt], 0, 0, 0);
      }
    }
    // attn-out -> swizzled ao (wave-own rows), cols h*32 + dt*16 + c
    #pragma unroll
    for (int dt = 0; dt < 2; ++dt) {
      int gr0 = h * 4 + dt * 2 + (c >> 3);
      #pragma unroll
      for (int rr = 0; rr < 4; ++rr) {
        int tok = wq * 16 + g * 4 + rr;
        if (tok < NWIN)
          ao[tok * 384 + (((gr0 ^ (tok & 15)) << 3) | (c & 7))] = f2bf(pacc[dt][rr]);
      }
    }
    __syncthreads();                   // attention reads done; next head may overwrite
  }

  // ================= fused proj: A (attn-out) -> regs, B from global, 0 barriers ====
  #pragma unroll
  for (int mt = 0; mt < 2; ++mt) {
    int row = wm * 32 + mt * 16 + c;
    int rc = row < NWIN ? row : 0;     // garbage rows masked at store
    #pragma unroll
    for (int kg = 0; kg < 12; ++kg)
      areg[mt][kg] = *(const bf16x8*)&ao[rc * 384 + (((kg * 4 + g) ^ (rc & 15)) << 3)];
  }
  for (int nb = 0; nb < 12; ++nb) {
    const int col = nb * 32 + wn * 16 + c;
    const ushort* bsrc = wpb + (size_t)col * DIM + g * 8;
    bf16x8 breg[12];
    #pragma unroll
    for (int kg = 0; kg < 12; ++kg)
      breg[kg] = *(const bf16x8*)(bsrc + kg * 32);
    f32x4 acc[2] = {};
    #pragma unroll
    for (int kg = 0; kg < 12; ++kg) {
      acc[0] = __builtin_amdgcn_mfma_f32_16x16x32_bf16(areg[0][kg], breg[kg], acc[0], 0, 0, 0);
      acc[1] = __builtin_amdgcn_mfma_f32_16x16x32_bf16(areg[1][kg], breg[kg], acc[1], 0, 0, 0);
    }
    float pb = proj_b[col];
    #pragma unroll
    for (int mt = 0; mt < 2; ++mt) {
      #pragma unroll
      for (int r = 0; r < 4; ++r) {
        int tok = wm * 32 + mt * 16 + g * 4 + r;
        if (tok < NWIN)
          out[((size_t)blk * NWIN + tok) * DIM + col] = acc[mt][r] + pb;
      }
    }
  }
}

extern "C" void kernel_launch(void* const* d_in, const int* in_sizes, int n_in,
                              void* d_out, int out_size, void* d_ws, size_t ws_size,
                              hipStream_t stream) {
  const float* x          = (const float*)d_in[0];
  const float* mask       = (const float*)d_in[1];
  const float* bias_table = (const float*)d_in[2];
  const float* qkv_w      = (const float*)d_in[3];
  const float* qkv_b      = (const float*)d_in[4];
  const float* proj_w     = (const float*)d_in[5];
  const float* proj_b     = (const float*)d_in[6];
  const int*   rel_index  = (const int*)d_in[7];
  float* out = (float*)d_out;

  // ws: wqb @0 (884736 B) | wpb @884736 (294912) | qbF @1179648 (4608) | bmF @1184256 (12582912)
  ushort* wqb = (ushort*)d_ws;
  ushort* wpb = (ushort*)((char*)d_ws + 884736);
  float*  qbF = (float*)((char*)d_ws + 1179648);
  float*  bmF = (float*)((char*)d_ws + 1184256);

  prep_kernel<<<1024, 256, 0, stream>>>(qkv_w, proj_w, bias_table, rel_index, mask, qkv_b,
                                        wqb, wpb, qbF, bmF);
  winattn_kernel<<<4096, 256, 0, stream>>>(x, qbF, proj_b, wqb, wpb, bmF, out);
}

// Round 8
// 798.575 us; speedup vs baseline: 1.5907x; 1.5907x over previous
//
#include <hip/hip_runtime.h>
#include <hip/hip_bf16.h>

#define DIM   384
#define NWIN  49
#define HEADS 12
#define SCALE 0.17677669529663687f

typedef unsigned short ushort;
using bf16x8 = __attribute__((ext_vector_type(8))) short;
using u16x4  = __attribute__((ext_vector_type(4))) ushort;
using f32x4  = __attribute__((ext_vector_type(4))) float;

__device__ __forceinline__ ushort f2bf(float f) {
  unsigned u = __float_as_uint(f);
  u += 0x7fff + ((u >> 16) & 1);          // RNE
  return (ushort)(u >> 16);
}

typedef __attribute__((address_space(1))) const void gas_void;
typedef __attribute__((address_space(3))) void las_void;

__device__ __forceinline__ void gload16(const ushort* g, ushort* l) {
  __builtin_amdgcn_global_load_lds((gas_void*)g, (las_void*)l, 16, 0, 0);
}

// ===================== prep =====================
__global__ void prep_kernel(const float* __restrict__ qkv_w, const float* __restrict__ proj_w,
                            const float* __restrict__ bias_table, const int* __restrict__ rel_index,
                            const float* __restrict__ mask, const float* __restrict__ qkv_b,
                            ushort* __restrict__ wqb, ushort* __restrict__ wpb,
                            float* __restrict__ qbF, float* __restrict__ bmF) {
  int i0 = blockIdx.x * 256 + threadIdx.x;
  int stride = gridDim.x * 256;
  for (int i = i0; i < 1152 * 384; i += stride) {
    float v = qkv_w[i];
    if (i < 384 * 384) v *= SCALE;                 // fold softmax scale into Wq
    wqb[i] = f2bf(v);
  }
  for (int i = i0; i < 384 * 384; i += stride) wpb[i] = f2bf(proj_w[i]);
  for (int i = i0; i < 1152; i += stride) qbF[i] = qkv_b[i] * (i < 384 ? SCALE : 1.f);
  // bmF[wdx][h][wq][kt][lane][r], masking baked in
  for (int i = i0; i < 64 * HEADS * 4 * 4 * 64 * 4; i += stride) {
    int r = i & 3, lane = (i >> 2) & 63, kt = (i >> 8) & 3, wq = (i >> 10) & 3;
    int hw = i >> 12;
    int h = hw % HEADS, wdx = hw / HEADS;
    int q = wq * 16 + (lane >> 4) * 4 + r;
    int key = kt * 16 + (lane & 15);
    float v;
    if (q < NWIN)
      v = (key < NWIN) ? bias_table[rel_index[q * NWIN + key] * HEADS + h]
                         + mask[wdx * (NWIN * NWIN) + q * NWIN + key]
                       : -3.0e38f;
    else
      v = 0.f;
    bmF[i] = v;
  }
}

// ===================== kernel 2: QKV GEMM + attention (1 window/block) =====================
// LDS 63.1 KB -> 2 blocks/CU. attn-out -> global bf16.
__global__ __launch_bounds__(256, 2) void qkv_attn_kernel(
    const float* __restrict__ x, const float* __restrict__ qbF,
    const ushort* __restrict__ wqb, const float* __restrict__ bmF,
    ushort* __restrict__ aog)
{
  __shared__ ushort wb[2 * 12288];   // 2 x [96][128] weight chunks (x staged here first)
  __shared__ ushort qs[64 * 36];     // q rows, later P rows
  __shared__ ushort ks[64 * 36];
  __shared__ ushort vt[32 * 74];     // v^T [d][tok]

  const int blk = blockIdx.x;
  const int tid = threadIdx.x;
  const int w = tid >> 6, l = tid & 63;
  const int c = l & 15, g = l >> 4;
  const int wm = w >> 1, wn = w & 1;    // GEMM: 2M x 2N, wave tile 32 x 48
  const int wq = w;                     // attention: wave = q-tile
  const int wdx = blk & 63;
  const float LOG2E = 1.4426950408889634f;

  auto stage_qkv = [&](int h, int kc, int buf) {
    #pragma unroll
    for (int s = 0; s < 6; ++s) {
      int i = s * 256 + tid;            // 1536 granules exactly
      int n = i >> 4, g16 = i & 15;
      int grow = (n >> 5) * 384 + h * 32 + (n & 31);
      int sg = (g16 & 8) | ((g16 & 7) ^ (n & 7));
      gload16(wqb + (size_t)grow * DIM + kc * 128 + (sg << 3),
              wb + buf * 12288 + i * 8);
    }
  };

  bf16x8 areg[2][12] = {};
  auto compute_qkv = [&](int kcC, int buf, f32x4 (&acc)[2][3]) {
    const ushort* wcb = wb + buf * 12288;
    #pragma unroll
    for (int kk = 0; kk < 4; ++kk) {
      int sB = ((kk * 4 + g) ^ (c & 7)) << 3;
      #pragma unroll
      for (int nt = 0; nt < 3; ++nt) {
        int n = (wn * 3 + nt) * 16 + c;
        bf16x8 bb = *(const bf16x8*)&wcb[n * 128 + sB];
        acc[0][nt] = __builtin_amdgcn_mfma_f32_16x16x32_bf16(areg[0][kcC * 4 + kk], bb, acc[0][nt], 0, 0, 0);
        acc[1][nt] = __builtin_amdgcn_mfma_f32_16x16x32_bf16(areg[1][kcC * 4 + kk], bb, acc[1][nt], 0, 0, 0);
      }
    }
  };

  // ---- prologue
  {
    const float* xb = x + (size_t)blk * (NWIN * DIM);
    for (int i = tid; i < 4704; i += 256) {
      float4 f = ((const float4*)xb)[i];
      int row = i / 96, c4 = i - row * 96;
      u16x4 v4 = { f2bf(f.x), f2bf(f.y), f2bf(f.z), f2bf(f.w) };
      *(u16x4*)&wb[row * 384 + c4 * 4] = v4;
    }
  }
  __syncthreads();
  #pragma unroll
  for (int mt = 0; mt < 2; ++mt) {
    int row = wm * 32 + mt * 16 + c;
    if (row < NWIN) {
      #pragma unroll
      for (int kg = 0; kg < 12; ++kg)
        areg[mt][kg] = *(const bf16x8*)&wb[row * 384 + kg * 32 + g * 8];
    }
  }
  __syncthreads();
  stage_qkv(0, 0, 0);
  stage_qkv(0, 1, 1);
  __syncthreads();

  // ================= per-head loop =================
  for (int h = 0; h < HEADS; ++h) {
    f32x4 acc[2][3] = {};
    const int par = h & 1;

    compute_qkv(0, par, acc);
    __syncthreads();
    stage_qkv(h, 2, par);

    compute_qkv(1, par ^ 1, acc);
    __syncthreads();
    if (h < 11) stage_qkv(h + 1, 0, par ^ 1);

    compute_qkv(2, par, acc);
    __syncthreads();
    if (h < 11) stage_qkv(h + 1, 1, par);

    #pragma unroll
    for (int nt = 0; nt < 3; ++nt) {
      int gnt = wn * 3 + nt;
      int which = gnt >> 1;
      int d = (gnt & 1) * 16 + c;
      float qb_ = qbF[which * 384 + h * 32 + d];
      #pragma unroll
      for (int mt = 0; mt < 2; ++mt) {
        #pragma unroll
        for (int r = 0; r < 4; ++r) {
          int tok = wm * 32 + mt * 16 + g * 4 + r;
          float v = acc[mt][nt][r] + qb_;
          if (which == 0)      qs[tok * 36 + d] = f2bf(v);
          else if (which == 1) ks[tok * 36 + d] = f2bf(v);
          else                 vt[d * 74 + tok] = f2bf(v);
        }
      }
    }
    __syncthreads();

    // ---- attention (wave = q-tile wq); FIXED bias index (verified *1024 form)
    const f32x4* bw4 = (const f32x4*)(bmF + ((((size_t)(wdx * HEADS + h)) * 4 + wq) * 4 * 64 + l) * 4);
    f32x4 bmv[4];
    #pragma unroll
    for (int kt = 0; kt < 4; ++kt) bmv[kt] = bw4[kt * 64];

    f32x4 sacc[4] = {};
    {
      bf16x8 aq = *(const bf16x8*)&qs[(wq * 16 + c) * 36 + g * 8];
      #pragma unroll
      for (int kt = 0; kt < 4; ++kt) {
        bf16x8 bk = *(const bf16x8*)&ks[(kt * 16 + c) * 36 + g * 8];
        sacc[kt] = __builtin_amdgcn_mfma_f32_16x16x32_bf16(aq, bk, sacc[kt], 0, 0, 0);
      }
    }
    float p[4][4];
    #pragma unroll
    for (int r = 0; r < 4; ++r) {
      float s0 = sacc[0][r] + bmv[0][r], s1 = sacc[1][r] + bmv[1][r];
      float s2 = sacc[2][r] + bmv[2][r], s3 = sacc[3][r] + bmv[3][r];
      float mx = fmaxf(fmaxf(s0, s1), fmaxf(s2, s3));
      mx = fmaxf(mx, __shfl_xor(mx, 1, 64));
      mx = fmaxf(mx, __shfl_xor(mx, 2, 64));
      mx = fmaxf(mx, __shfl_xor(mx, 4, 64));
      mx = fmaxf(mx, __shfl_xor(mx, 8, 64));
      float p0 = __builtin_exp2f((s0 - mx) * LOG2E);
      float p1 = __builtin_exp2f((s1 - mx) * LOG2E);
      float p2 = __builtin_exp2f((s2 - mx) * LOG2E);
      float p3 = __builtin_exp2f((s3 - mx) * LOG2E);
      float sum = p0 + p1 + p2 + p3;
      sum += __shfl_xor(sum, 1, 64);
      sum += __shfl_xor(sum, 2, 64);
      sum += __shfl_xor(sum, 4, 64);
      sum += __shfl_xor(sum, 8, 64);
      float inv = 1.0f / sum;
      p[0][r] = p0 * inv; p[1][r] = p1 * inv; p[2][r] = p2 * inv; p[3][r] = p3 * inv;
    }
    f32x4 pacc[2] = {};
    #pragma unroll
    for (int kkh = 0; kkh < 2; ++kkh) {
      #pragma unroll
      for (int t = 0; t < 2; ++t) {
        int kt = kkh * 2 + t;
        #pragma unroll
        for (int r = 0; r < 4; ++r)
          qs[(wq * 16 + g * 4 + r) * 36 + t * 16 + c] = f2bf(p[kt][r]);
      }
      bf16x8 ap = *(const bf16x8*)&qs[(wq * 16 + c) * 36 + g * 8];
      #pragma unroll
      for (int dt = 0; dt < 2; ++dt) {
        bf16x8 bv = *(const bf16x8*)&vt[(dt * 16 + c) * 74 + kkh * 32 + g * 8];
        pacc[dt] = __builtin_amdgcn_mfma_f32_16x16x32_bf16(ap, bv, pacc[dt], 0, 0, 0);
      }
    }
    #pragma unroll
    for (int dt = 0; dt < 2; ++dt) {
      #pragma unroll
      for (int rr = 0; rr < 4; ++rr) {
        int tok = wq * 16 + g * 4 + rr;
        if (tok < NWIN)
          aog[((size_t)blk * NWIN + tok) * DIM + h * 32 + dt * 16 + c] = f2bf(pacc[dt][rr]);
      }
    }
    __syncthreads();
  }
}

// ===================== kernel 3: proj GEMM 128x128, K=384 =====================
__global__ __launch_bounds__(256, 2) void proj_kernel(
    const ushort* __restrict__ ao, const ushort* __restrict__ wpb,
    const float* __restrict__ proj_b, float* __restrict__ out)
{
  extern __shared__ ushort sm3[];
  ushort* lA = sm3;                  // 2 x [128][64]
  ushort* lB = sm3 + 16384;          // 2 x [128][64]

  const int blk = blockIdx.x;
  const int bM = blk / 3, bN = blk - bM * 3;
  const int m0 = bM * 128, n0 = bN * 128;
  const int tid = threadIdx.x;
  const int w = tid >> 6, l = tid & 63;
  const int c = l & 15, g = l >> 4;
  const int wm = w >> 1, wn = w & 1;   // wave tile 64 x 64

  auto stageA = [&](int kc, int buf) {
    #pragma unroll
    for (int s = 0; s < 4; ++s) {
      int i = s * 256 + tid;
      int row = i >> 3, g16 = i & 7;
      gload16(ao + (size_t)(m0 + row) * DIM + kc * 64 + ((g16 ^ (row & 7)) << 3),
              lA + buf * 8192 + i * 8);
    }
  };
  auto stageB = [&](int kc, int buf) {
    #pragma unroll
    for (int s = 0; s < 4; ++s) {
      int i = s * 256 + tid;
      int row = i >> 3, g16 = i & 7;
      gload16(wpb + (size_t)(n0 + row) * DIM + kc * 64 + ((g16 ^ (row & 7)) << 3),
              lB + buf * 8192 + i * 8);
    }
  };

  f32x4 acc[4][4] = {};
  stageA(0, 0); stageB(0, 0);
  stageA(1, 1); stageB(1, 1);
  __syncthreads();

  for (int kc = 0; kc < 6; ++kc) {
    const ushort* A = lA + (kc & 1) * 8192;
    const ushort* B = lB + (kc & 1) * 8192;
    #pragma unroll
    for (int kk = 0; kk < 2; ++kk) {
      int swz = ((kk * 4 + g) ^ (c & 7)) << 3;
      bf16x8 af[4], bfr[4];
      #pragma unroll
      for (int mt = 0; mt < 4; ++mt)
        af[mt] = *(const bf16x8*)&A[(wm * 64 + mt * 16 + c) * 64 + swz];
      #pragma unroll
      for (int nt = 0; nt < 4; ++nt)
        bfr[nt] = *(const bf16x8*)&B[(wn * 64 + nt * 16 + c) * 64 + swz];
      #pragma unroll
      for (int mt = 0; mt < 4; ++mt)
        #pragma unroll
        for (int nt = 0; nt < 4; ++nt)
          acc[mt][nt] = __builtin_amdgcn_mfma_f32_16x16x32_bf16(af[mt], bfr[nt], acc[mt][nt], 0, 0, 0);
    }
    __syncthreads();
    if (kc + 2 < 6) { stageA(kc + 2, kc & 1); stageB(kc + 2, kc & 1); }
  }

  #pragma unroll
  for (int nt = 0; nt < 4; ++nt) {
    int col = n0 + wn * 64 + nt * 16 + c;
    float pb = proj_b[col];
    #pragma unroll
    for (int mt = 0; mt < 4; ++mt) {
      #pragma unroll
      for (int r = 0; r < 4; ++r) {
        int row = m0 + wm * 64 + mt * 16 + g * 4 + r;
        out[(size_t)row * DIM + col] = acc[mt][nt][r] + pb;
      }
    }
  }
}

// ===================== fallback: EXACT r5-passed monolith + bmF bias =====================
#define WB_OFF 0
#define QS_OFF 24576
#define KS_OFF 29696
#define VT_OFF 34816
#define AO_OFF 39424
#define SMEM_US 77056   // 154112 bytes

__global__ __launch_bounds__(512, 2) void winattn_fused(
    const float* __restrict__ x, const float* __restrict__ qbF,
    const float* __restrict__ proj_b, const ushort* __restrict__ wqb,
    const ushort* __restrict__ wpb, const float* __restrict__ bmF,
    float* __restrict__ out)
{
  extern __shared__ ushort smem[];
  ushort* wb = smem + WB_OFF;
  ushort* ao = smem + AO_OFF;

  const int blk = blockIdx.x;
  const int tid = threadIdx.x;
  const int w = tid >> 6, l = tid & 63;
  const int c = l & 15, g = l >> 4;
  const int wm = w >> 1, wn = w & 1;
  const int win = w >> 2, wq = w & 3;
  const float LOG2E = 1.4426950408889634f;

  ushort* qsw = smem + QS_OFF + win * 2560;
  ushort* ksw = smem + KS_OFF + win * 2560;
  ushort* vtw = smem + VT_OFF + win * 2304;
  ushort* psw = qsw;

  auto stage_qkv = [&](int h, int kc, int buf) {
    #pragma unroll
    for (int s = 0; s < 3; ++s) {
      int i = s * 512 + tid;
      int n = i >> 4, g16 = i & 15;
      int grow = (n >> 5) * 384 + h * 32 + (n & 31);
      int sg = (g16 & 8) | ((g16 & 7) ^ (n & 7));
      gload16(wqb + (size_t)grow * DIM + kc * 128 + (sg << 3), wb + buf * 12288 + i * 8);
    }
  };
  auto stage_proj = [&](int nb, int kc, int buf) {
    #pragma unroll
    for (int s = 0; s < 3; ++s) {
      int i = s * 512 + tid;
      int n = i >> 4, g16 = i & 15;
      int grow = nb * 96 + n;
      int sg = (g16 & 8) | ((g16 & 7) ^ (n & 7));
      gload16(wpb + (size_t)grow * DIM + kc * 128 + (sg << 3), wb + buf * 12288 + i * 8);
    }
  };

  bf16x8 areg[2][12] = {};
  auto compute_qkv = [&](int kcC, int buf, f32x4 (&acc)[2][3]) {
    const ushort* wcb = wb + buf * 12288;
    #pragma unroll
    for (int kk = 0; kk < 4; ++kk) {
      int sB = ((kk * 4 + g) ^ (c & 7)) << 3;
      #pragma unroll
      for (int nt = 0; nt < 3; ++nt) {
        int n = (wn * 3 + nt) * 16 + c;
        bf16x8 bb = *(const bf16x8*)&wcb[n * 128 + sB];
        acc[0][nt] = __builtin_amdgcn_mfma_f32_16x16x32_bf16(areg[0][kcC * 4 + kk], bb, acc[0][nt], 0, 0, 0);
        acc[1][nt] = __builtin_amdgcn_mfma_f32_16x16x32_bf16(areg[1][kcC * 4 + kk], bb, acc[1][nt], 0, 0, 0);
      }
    }
  };
  auto compute_proj = [&](int kcC, int buf, f32x4 (&acc)[2][3]) {
    const ushort* wcb = wb + buf * 12288;
    int r0 = wm * 32 + c;      if (r0 >= 98) r0 -= 64;
    int r1 = wm * 32 + 16 + c; if (r1 >= 98) r1 -= 64;
    #pragma unroll
    for (int kk = 0; kk < 4; ++kk) {
      int p = kcC * 16 + kk * 4 + g;
      int sw = (p ^ (c & 7)) << 3;
      bf16x8 a0 = *(const bf16x8*)&ao[r0 * 384 + sw];
      bf16x8 a1 = *(const bf16x8*)&ao[r1 * 384 + sw];
      int sB = ((kk * 4 + g) ^ (c & 7)) << 3;
      #pragma unroll
      for (int nt = 0; nt < 3; ++nt) {
        int n = (wn * 3 + nt) * 16 + c;
        bf16x8 bb = *(const bf16x8*)&wcb[n * 128 + sB];
        acc[0][nt] = __builtin_amdgcn_mfma_f32_16x16x32_bf16(a0, bb, acc[0][nt], 0, 0, 0);
        acc[1][nt] = __builtin_amdgcn_mfma_f32_16x16x32_bf16(a1, bb, acc[1][nt], 0, 0, 0);
      }
    }
  };

  stage_qkv(0, 0, 0);
  stage_qkv(0, 1, 1);
  {
    const float* xb = x + (size_t)blk * (2 * NWIN * DIM);
    for (int i = tid; i < 9408; i += 512) {
      float4 f = ((const float4*)xb)[i];
      int row = i / 96, c4 = i - row * 96;
      int k = c4 * 4;
      int gr = k >> 3;
      u16x4 v4 = { f2bf(f.x), f2bf(f.y), f2bf(f.z), f2bf(f.w) };
      *(u16x4*)&ao[row * 384 + ((gr ^ (row & 7)) << 3) + (k & 7)] = v4;
    }
  }
  __syncthreads();
  #pragma unroll
  for (int mt = 0; mt < 2; ++mt) {
    int row = wm * 32 + mt * 16 + c;
    int wi = row >> 6, tok = row & 63;
    if (tok < NWIN) {
      int ar = wi * 49 + tok;
      #pragma unroll
      for (int kg = 0; kg < 12; ++kg)
        areg[mt][kg] = *(const bf16x8*)&ao[ar * 384 + (((kg * 4 + g) ^ (ar & 7)) << 3)];
    }
  }

  for (int h = 0; h < HEADS; ++h) {
    f32x4 acc[2][3] = {};
    const int par = h & 1;
    compute_qkv(0, par, acc);
    __syncthreads();
    stage_qkv(h, 2, par);
    compute_qkv(1, par ^ 1, acc);
    __syncthreads();
    if (h < 11) stage_qkv(h + 1, 0, par ^ 1); else stage_proj(0, 0, par ^ 1);
    compute_qkv(2, par, acc);
    __syncthreads();
    if (h < 11) stage_qkv(h + 1, 1, par); else stage_proj(0, 1, par);
    {
      int winE = wm >> 1;
      ushort* qsE = smem + QS_OFF + winE * 2560;
      ushort* ksE = smem + KS_OFF + winE * 2560;
      ushort* vtE = smem + VT_OFF + winE * 2304;
      #pragma unroll
      for (int nt = 0; nt < 3; ++nt) {
        int gnt = wn * 3 + nt;
        int which = gnt >> 1;
        int d = (gnt & 1) * 16 + c;
        float qb_ = qbF[which * 384 + h * 32 + d];
        #pragma unroll
        for (int mt = 0; mt < 2; ++mt) {
          #pragma unroll
          for (int r = 0; r < 4; ++r) {
            int tok = (wm & 1) * 32 + mt * 16 + g * 4 + r;
            float v = acc[mt][nt][r] + qb_;
            if (which == 0)      qsE[tok * 40 + d] = f2bf(v);
            else if (which == 1) ksE[tok * 40 + d] = f2bf(v);
            else                 vtE[d * 72 + tok] = f2bf(v);
          }
        }
      }
    }
    __syncthreads();

    const int wdx = ((blk << 1) + win) & 63;
    const f32x4* bw4 = (const f32x4*)(bmF + ((((size_t)(wdx * HEADS + h)) * 4 + wq) * 4 * 64 + l) * 4);
    f32x4 bmv[4];
    #pragma unroll
    for (int kt = 0; kt < 4; ++kt) bmv[kt] = bw4[kt * 64];

    f32x4 sacc[4] = {};
    {
      bf16x8 aq = *(const bf16x8*)&qsw[(wq * 16 + c) * 40 + g * 8];
      #pragma unroll
      for (int kt = 0; kt < 4; ++kt) {
        bf16x8 bk = *(const bf16x8*)&ksw[(kt * 16 + c) * 40 + g * 8];
        sacc[kt] = __builtin_amdgcn_mfma_f32_16x16x32_bf16(aq, bk, sacc[kt], 0, 0, 0);
      }
    }
    float p[4][4];
    #pragma unroll
    for (int r = 0; r < 4; ++r) {
      float s0 = sacc[0][r] + bmv[0][r], s1 = sacc[1][r] + bmv[1][r];
      float s2 = sacc[2][r] + bmv[2][r], s3 = sacc[3][r] + bmv[3][r];
      float mx = fmaxf(fmaxf(s0, s1), fmaxf(s2, s3));
      mx = fmaxf(mx, __shfl_xor(mx, 1, 64));
      mx = fmaxf(mx, __shfl_xor(mx, 2, 64));
      mx = fmaxf(mx, __shfl_xor(mx, 4, 64));
      mx = fmaxf(mx, __shfl_xor(mx, 8, 64));
      float p0 = __builtin_exp2f((s0 - mx) * LOG2E);
      float p1 = __builtin_exp2f((s1 - mx) * LOG2E);
      float p2 = __builtin_exp2f((s2 - mx) * LOG2E);
      float p3 = __builtin_exp2f((s3 - mx) * LOG2E);
      float sum = p0 + p1 + p2 + p3;
      sum += __shfl_xor(sum, 1, 64);
      sum += __shfl_xor(sum, 2, 64);
      sum += __shfl_xor(sum, 4, 64);
      sum += __shfl_xor(sum, 8, 64);
      float inv = 1.0f / sum;
      p[0][r] = p0 * inv; p[1][r] = p1 * inv; p[2][r] = p2 * inv; p[3][r] = p3 * inv;
    }
    f32x4 pacc2[2] = {};
    #pragma unroll
    for (int kkh = 0; kkh < 2; ++kkh) {
      #pragma unroll
      for (int t = 0; t < 2; ++t) {
        int kt = kkh * 2 + t;
        #pragma unroll
        for (int r = 0; r < 4; ++r)
          psw[(wq * 16 + g * 4 + r) * 40 + t * 16 + c] = f2bf(p[kt][r]);
      }
      bf16x8 ap = *(const bf16x8*)&psw[(wq * 16 + c) * 40 + g * 8];
      #pragma unroll
      for (int dt = 0; dt < 2; ++dt) {
        bf16x8 bv = *(const bf16x8*)&vtw[(dt * 16 + c) * 72 + kkh * 32 + g * 8];
        pacc2[dt] = __builtin_amdgcn_mfma_f32_16x16x32_bf16(ap, bv, pacc2[dt], 0, 0, 0);
      }
    }
    #pragma unroll
    for (int dt = 0; dt < 2; ++dt) {
      int gr0 = h * 4 + dt * 2 + (c >> 3);
      #pragma unroll
      for (int rr = 0; rr < 4; ++rr) {
        int tok = wq * 16 + g * 4 + rr;
        int row0 = win * 49 + tok;
        if (tok < NWIN)
          ao[row0 * 384 + (((gr0 ^ (row0 & 7)) << 3) | (c & 7))] = f2bf(pacc2[dt][rr]);
      }
    }
    __syncthreads();
  }

  __syncthreads();
  for (int nb = 0; nb < 4; ++nb) {
    f32x4 acc[2][3] = {};
    const int pb0 = (nb * 3) & 1;
    compute_proj(0, pb0, acc);
    __syncthreads();
    stage_proj(nb, 2, pb0);
    compute_proj(1, pb0 ^ 1, acc);
    __syncthreads();
    if (nb < 3) stage_proj(nb + 1, 0, pb0 ^ 1);
    compute_proj(2, pb0, acc);
    __syncthreads();
    if (nb < 3) stage_proj(nb + 1, 1, pb0);
    #pragma unroll
    for (int nt = 0; nt < 3; ++nt) {
      int col = nb * 96 + (wn * 3 + nt) * 16 + c;
      float pb = proj_b[col];
      #pragma unroll
      for (int mt = 0; mt < 2; ++mt) {
        #pragma unroll
        for (int r = 0; r < 4; ++r) {
          int mrow = wm * 32 + mt * 16 + g * 4 + r;
          if (mrow < 98) {
            int wi = mrow >= NWIN;
            int tok = mrow - (wi ? NWIN : 0);
            out[((size_t)((blk << 1) + wi) * NWIN + tok) * DIM + col] = acc[mt][nt][r] + pb;
          }
        }
      }
    }
  }
}

extern "C" void kernel_launch(void* const* d_in, const int* in_sizes, int n_in,
                              void* d_out, int out_size, void* d_ws, size_t ws_size,
                              hipStream_t stream) {
  const float* x          = (const float*)d_in[0];
  const float* mask       = (const float*)d_in[1];
  const float* bias_table = (const float*)d_in[2];
  const float* qkv_w      = (const float*)d_in[3];
  const float* qkv_b      = (const float*)d_in[4];
  const float* proj_w     = (const float*)d_in[5];
  const float* proj_b     = (const float*)d_in[6];
  const int*   rel_index  = (const int*)d_in[7];
  float* out = (float*)d_out;

  // ws: wqb @0 | wpb @884736 | qbF @1179648 | bmF @1184256 | aog @13767168 (154140672 B)
  ushort* wqb = (ushort*)d_ws;
  ushort* wpb = (ushort*)((char*)d_ws + 884736);
  float*  qbF = (float*)((char*)d_ws + 1179648);
  float*  bmF = (float*)((char*)d_ws + 1184256);
  ushort* aog = (ushort*)((char*)d_ws + 13767168);
  const size_t NEED = 13767168ull + 154140672ull;

  prep_kernel<<<1024, 256, 0, stream>>>(qkv_w, proj_w, bias_table, rel_index, mask, qkv_b,
                                        wqb, wpb, qbF, bmF);

  if (ws_size >= NEED) {
    qkv_attn_kernel<<<4096, 256, 0, stream>>>(x, qbF, wqb, bmF, aog);
    hipFuncSetAttribute((const void*)proj_kernel,
                        hipFuncAttributeMaxDynamicSharedMemorySize, 65536);
    proj_kernel<<<4704, 256, 65536, stream>>>(aog, wpb, proj_b, out);
  } else {
    hipFuncSetAttribute((const void*)winattn_fused,
                        hipFuncAttributeMaxDynamicSharedMemorySize, SMEM_US * 2);
    winattn_fused<<<2048, 512, SMEM_US * 2, stream>>>(x, qbF, proj_b, wqb, wpb, bmF, out);
  }
}